// Round 19
// baseline (166.347 us; speedup 1.0000x reference)
//
#include <hip/hip_runtime.h>
#include <hip/hip_bf16.h>

// ---------------------------------------------------------------------------
// SelfAttention fused pipeline for MI355X (gfx950)
//   QKV GEMM 256x192 6-phase, triple-buffered B (R19: every staged load has
//   >=4 phases of runway; gates vmcnt(7) @P3/P6); f32 Q/K + bf16 V^T epilogue;
//   wide table RoPE; bf16 MFMA attention (no-max log2 softmax); projection
//   GEMM 256x128 (256 blocks full fill).
// ---------------------------------------------------------------------------

typedef __attribute__((ext_vector_type(4))) float f32x4;
typedef __attribute__((ext_vector_type(8))) short short8;

#define AS1C(p) ((const __attribute__((address_space(1))) void*)(p))
#define AS3(p)  ((__attribute__((address_space(3))) void*)(p))

__device__ __forceinline__ unsigned short f2bf(float f) {
  union { float f; unsigned int u; } x; x.f = f;
  unsigned int r = x.u + 0x7FFFu + ((x.u >> 16) & 1u);
  return (unsigned short)(r >> 16);
}

__device__ __forceinline__ unsigned short bfc(float f) {
  return __bfloat16_as_ushort(__float2bfloat16(f));
}

__device__ __forceinline__ float ex2(float x) {
  return __builtin_amdgcn_exp2f(x);
}

// -------------------- RoPE table: tab[t*32+i] = (cos, sin) ------------------
__global__ void rope_tab_kernel(float2* __restrict__ tab) {
  const int idx = blockIdx.x * 256 + threadIdx.x;  // 32768
  const int t = idx >> 5, i = idx & 31;
  const float invf = exp2f(-(float)i * 0.41524101186092029f);
  float sv, cv;
  __sincosf((float)t * invf, &sv, &cv);
  tab[idx] = make_float2(cv, sv);
}

// -------------------- x : f32 -> bf16 (vectorized) -------------------------
__global__ void cvt_bf16_kernel(const float* __restrict__ src,
                                unsigned short* __restrict__ dst, int n4) {
  int i = blockIdx.x * blockDim.x + threadIdx.x;
  if (i >= n4) return;
  const f32x4 v = *(const f32x4*)(src + (size_t)i * 4);
  ushort4 u = make_ushort4(f2bf(v[0]), f2bf(v[1]), f2bf(v[2]), f2bf(v[3]));
  *(ushort4*)(dst + (size_t)i * 4) = u;
}

// -- fused W transpose: z=0 Wq(*qs) z=1 Wk z=2 Wv -> Wt; z=3 Wp -> Wpt -------
__global__ void transpose_w_kernel(const float* __restrict__ Wq,
                                   const float* __restrict__ Wk,
                                   const float* __restrict__ Wv,
                                   const float* __restrict__ Wp,
                                   unsigned short* __restrict__ Wt,
                                   unsigned short* __restrict__ Wpt) {
  __shared__ float tile[32][33];
  const int z = blockIdx.z;
  const float* src;
  unsigned short* dst;
  int N, rowOff;
  float scale = 1.0f;
  if (z == 0)      { src = Wq; dst = Wt;  N = 2048; rowOff = 0;    scale = 0.18033688011112042f; }
  else if (z == 1) { src = Wk; dst = Wt;  N = 512;  rowOff = 2048; }
  else if (z == 2) { src = Wv; dst = Wt;  N = 512;  rowOff = 2560; }
  else             { src = Wp; dst = Wpt; N = 2048; rowOff = 0;    }
  const int n0 = blockIdx.x * 32, k0 = blockIdx.y * 32;
  if (n0 >= N) return;
  const int tx = threadIdx.x & 31, ty = threadIdx.x >> 5;
#pragma unroll
  for (int i = ty; i < 32; i += 8)
    tile[i][tx] = src[(size_t)(k0 + i) * N + (n0 + tx)];
  __syncthreads();
#pragma unroll
  for (int i = ty; i < 32; i += 8)
    dst[(size_t)(rowOff + n0 + i) * 2048 + (k0 + tx)] = f2bf(tile[tx][i] * scale);
}

// ---- wide RoPE: reads qkf f32 [4096][2560], writes bf16 qb/kb --------------
__global__ void rope_cvt2_kernel(const float2* __restrict__ tab,
                                 const float* __restrict__ qkf,
                                 unsigned short* __restrict__ qb,
                                 unsigned short* __restrict__ kb) {
  const int idx = blockIdx.x * 256 + threadIdx.x;  // 4096*320
  const int m = idx / 320;
  const int p = idx - m * 320;
  const int t = m & 1023;
  unsigned short* dst;
  int srcCol, dcol;
  if (p < 256) { dcol = p * 8; srcCol = dcol; dst = qb + (size_t)m * 2048 + dcol; }
  else         { dcol = (p - 256) * 8; srcCol = 2048 + dcol; dst = kb + (size_t)m * 512 + dcol; }
  const int i0 = (srcCol & 63) >> 1;
  const float* src = qkf + (size_t)m * 2560 + srcCol;
  const f32x4 v0 = *(const f32x4*)(src);
  const f32x4 v1 = *(const f32x4*)(src + 4);
  float x[8] = {v0[0], v0[1], v0[2], v0[3], v1[0], v1[1], v1[2], v1[3]};
  short8 o;
#pragma unroll
  for (int j = 0; j < 4; ++j) {
    const float2 cs = tab[t * 32 + i0 + j];
    const float x1 = x[2 * j], x2 = x[2 * j + 1];
    o[2 * j]     = (short)bfc(x1 * cs.x - x2 * cs.y);
    o[2 * j + 1] = (short)bfc(x2 * cs.x + x1 * cs.y);
  }
  *(short8*)dst = o;
}

#define BAR() __builtin_amdgcn_s_barrier()

// =========== 256x192 QKV GEMM: 256 blocks, 8 waves = 4M x 2N ================
// LDS 136 KiB (shorts): A buf(par&1) @ par<<14 (256x64 each);
// B buf(tile%3) @ 32768 + (tile%3)*12288 (192x64 each).
// Granule-XOR swizzle both-sides; XCD-chunked block swizzle.
// 6 phases / 2 K-tiles; B triple-buffered so every staged load has >=4
// phases of runway; symmetric gates vmcnt(7) at P3 and P6.
#define SA3(tile, half)                                                                  \
  do {                                                                                   \
    const unsigned short* p_ = Ap + (size_t)(m0 + (half) * 128 + sr) * 2048 + (tile) * 64 + sc; \
    const int d_ = (((tile) & 1) << 14) + ((half) << 13) + tid * 8;                      \
    __builtin_amdgcn_global_load_lds(AS1C(p_), AS3(&S[d_]), 16, 0, 0);                   \
    __builtin_amdgcn_global_load_lds(AS1C(p_ + (size_t)64 * 2048), AS3(&S[d_ + 4096]), 16, 0, 0); \
  } while (0)

#define SB3(tile, u)                                                                     \
  do {                                                                                   \
    const unsigned short* p_ = Bp + (size_t)(n0 + (u) * 64 + sr) * 2048 + (tile) * 64 + sc; \
    const int d_ = 32768 + ((tile) % 3) * 12288 + (u) * 4096 + tid * 8;                  \
    __builtin_amdgcn_global_load_lds(AS1C(p_), AS3(&S[d_]), 16, 0, 0);                   \
  } while (0)

#define RDA3(tile)                                                                       \
  _Pragma("unroll") for (int kk = 0; kk < 2; ++kk)                                       \
  _Pragma("unroll") for (int fm = 0; fm < 4; ++fm) {                                     \
    const int r_ = mg * 64 + fm * 16 + l15;                                              \
    af[kk][fm] = *(const short8*)&S[(((tile) & 1) << 14) + r_ * 64 +                     \
                                    (((kk << 2) | lg) ^ (r_ & 7)) * 8];                  \
  }

#define RDB3(tile, p)                                                                    \
  _Pragma("unroll") for (int kk = 0; kk < 2; ++kk)                                       \
  _Pragma("unroll") for (int jj = 0; jj < 2; ++jj) {                                     \
    const int r_ = ng * 96 + ((p) * 2 + jj) * 16 + l15;                                  \
    bf[kk][jj] = *(const short8*)&S[32768 + ((tile) % 3) * 12288 + r_ * 64 +             \
                                    (((kk << 2) | lg) ^ (r_ & 7)) * 8];                  \
  }

#define MM3(p)                                                                           \
  do {                                                                                   \
    __builtin_amdgcn_s_setprio(1);                                                       \
    _Pragma("unroll") for (int kk = 0; kk < 2; ++kk)                                     \
    _Pragma("unroll") for (int fm = 0; fm < 4; ++fm)                                     \
    _Pragma("unroll") for (int jj = 0; jj < 2; ++jj)                                     \
      acc[fm][(p) * 2 + jj] = __builtin_amdgcn_mfma_f32_16x16x32_bf16(                   \
          af[kk][fm], bf[kk][jj], acc[fm][(p) * 2 + jj], 0, 0, 0);                       \
    __builtin_amdgcn_s_setprio(0);                                                       \
  } while (0)

__global__ __launch_bounds__(512, 1) void gemm256x192_qkv_kernel(
    const unsigned short* __restrict__ Ap, const unsigned short* __restrict__ Bp,
    float* __restrict__ qkf, unsigned short* __restrict__ vt) {
  __shared__ unsigned short S[69632];  // 136 KiB
  const int tid = threadIdx.x;
  const int lane = tid & 63, w = tid >> 6;
  const int l15 = lane & 15, lg = lane >> 4;
  int lid = blockIdx.x + 16 * blockIdx.y;          // 256 blocks
  lid = (lid & 7) * 32 + (lid >> 3);               // bijective XCD chunk
  const int m0 = (lid >> 4) * 256, n0 = (lid & 15) * 192;
  const int mg = w >> 1;   // 4 M-groups of 64 rows
  const int ng = w & 1;    // 2 N-groups of 96 cols
  const int sr = tid >> 3;
  const int sc = ((tid & 7) ^ (sr & 7)) << 3;
  const int NT = 32;       // K=2048

  f32x4 acc[4][6];
#pragma unroll
  for (int i = 0; i < 4; ++i)
#pragma unroll
    for (int j = 0; j < 6; ++j)
#pragma unroll
      for (int c = 0; c < 4; ++c) acc[i][j][c] = 0.f;

  // prologue: full B(0),A(0),B(1),A(1); gate retires tile-0's 7 loads
  SB3(0, 0); SB3(0, 1); SB3(0, 2); SA3(0, 0); SA3(0, 1);
  SB3(1, 0); SB3(1, 1); SB3(1, 2); SA3(1, 0); SA3(1, 1);
  asm volatile("s_waitcnt vmcnt(7)" ::: "memory");
  BAR();

  short8 af[2][4], bf[2][2];

  for (int t = 0; t < NT; t += 2) {
    const bool nl = (t + 2 < NT);
    // P1: read A(t), B(t)p0; stage B(t+2)u0,u1 (buf (t+2)%3 free since r-1)
    RDA3(t); RDB3(t, 0);
    if (nl) { SB3(t + 2, 0); SB3(t + 2, 1); }
    BAR();
    MM3(0);
    BAR();
    // P2: read B(t)p1; stage A(t+2)h0 (A(t) fully read P1), B(t+2)u2
    RDB3(t, 1);
    if (nl) { SA3(t + 2, 0); SB3(t + 2, 2); }
    BAR();
    MM3(1);
    BAR();
    // P3: read B(t)p2; stage A(t+2)h1; gate: retire last round's P4-P6 (7)
    RDB3(t, 2);
    if (nl) {
      SA3(t + 2, 1);
      asm volatile("s_waitcnt vmcnt(7)" ::: "memory");
    } else {
      asm volatile("s_waitcnt vmcnt(0)" ::: "memory");
    }
    BAR();
    MM3(2);
    BAR();
    // P4: read A(t+1), B(t+1)p0; stage B(t+3)u0 (buf t%3, reads drained P3)
    RDA3(t + 1); RDB3(t + 1, 0);
    if (nl) SB3(t + 3, 0);
    BAR();
    MM3(0);
    BAR();
    // P5: read B(t+1)p1; stage A(t+3)h0 (A(t+1) fully read P4), B(t+3)u1
    RDB3(t + 1, 1);
    if (nl) { SA3(t + 3, 0); SB3(t + 3, 1); }
    BAR();
    MM3(1);
    BAR();
    // P6: read B(t+1)p2; stage A(t+3)h1, B(t+3)u2; gate: retire P1-P3 (7)
    RDB3(t + 1, 2);
    if (nl) {
      SA3(t + 3, 1); SB3(t + 3, 2);
      asm volatile("s_waitcnt vmcnt(7)" ::: "memory");
    }
    BAR();
    MM3(2);
    BAR();
  }

  // epilogue: per-fragment region branch (boundaries are 16-col aligned)
#pragma unroll
  for (int fn = 0; fn < 6; ++fn) {
    const int col16 = n0 + ng * 96 + fn * 16;
    if (col16 < 2560) {
      // Q/K: coalesced f32 stores
#pragma unroll
      for (int fm = 0; fm < 4; ++fm) {
        const int row = m0 + mg * 64 + fm * 16 + lg * 4;
        const size_t base = (size_t)row * 2560 + col16 + l15;
#pragma unroll
        for (int r = 0; r < 4; ++r) qkf[base + (size_t)r * 2560] = acc[fm][fn][r];
      }
    } else {
      // V: packed transposed bf16 store
      const int dz = (col16 - 2560) >> 6;
      const int d = ((col16 - 2560) & 63) + l15;
#pragma unroll
      for (int fm = 0; fm < 4; ++fm) {
        const int row = m0 + mg * 64 + fm * 16 + lg * 4;
        const int z = (row >> 10) * 8 + dz;
        const int t0 = row & 1023;
        ushort4 u = make_ushort4(bfc(acc[fm][fn][0]), bfc(acc[fm][fn][1]),
                                 bfc(acc[fm][fn][2]), bfc(acc[fm][fn][3]));
        *(ushort4*)&vt[(size_t)z * 65536 + d * 1024 + t0] = u;
      }
    }
  }
}

// ============ 256x128 GEMM (projection): 8 waves 2Mx4N (32-col strips) ======
#define SA2(tile, half)                                                                  \
  do {                                                                                   \
    const unsigned short* p_ = Ap + (size_t)(m0 + (half) * 128 + sr) * Kd + (tile) * 64 + sc; \
    const int d_ = (((tile) & 1) << 14) + ((half) << 13) + tid * 8;                      \
    __builtin_amdgcn_global_load_lds(AS1C(p_), AS3(&S[d_]), 16, 0, 0);                   \
    __builtin_amdgcn_global_load_lds(AS1C(p_ + (size_t)64 * Kd), AS3(&S[d_ + 4096]), 16, 0, 0); \
  } while (0)

#define SB2(tile)                                                                        \
  do {                                                                                   \
    const unsigned short* p_ = Bp + (size_t)(n0 + sr) * Kd + (tile) * 64 + sc;           \
    const int d_ = 32768 + (((tile) & 1) << 13) + tid * 8;                               \
    __builtin_amdgcn_global_load_lds(AS1C(p_), AS3(&S[d_]), 16, 0, 0);                   \
    __builtin_amdgcn_global_load_lds(AS1C(p_ + (size_t)64 * Kd), AS3(&S[d_ + 4096]), 16, 0, 0); \
  } while (0)

#define RDA2(tile, Msub)                                                                 \
  _Pragma("unroll") for (int kk = 0; kk < 2; ++kk)                                       \
  _Pragma("unroll") for (int fm = 0; fm < 4; ++fm) {                                     \
    const int r_ = (Msub) * 64 + fm * 16 + l15;                                          \
    af[kk][fm] = *(const short8*)&S[(((tile) & 1) << 14) + (ah << 13) + r_ * 64 +        \
                                    (((kk << 2) | lg) ^ (r_ & 7)) * 8];                  \
  }

#define RDB2(dst, tile)                                                                  \
  _Pragma("unroll") for (int kk = 0; kk < 2; ++kk)                                       \
  _Pragma("unroll") for (int j = 0; j < 2; ++j) {                                        \
    const int r_ = wn + j * 16 + l15;                                                    \
    dst[kk][j] = *(const short8*)&S[32768 + (((tile) & 1) << 13) + r_ * 64 +             \
                                    (((kk << 2) | lg) ^ (r_ & 7)) * 8];                  \
  }

#define MM2(Msub, bb)                                                                    \
  do {                                                                                   \
    __builtin_amdgcn_s_setprio(1);                                                       \
    _Pragma("unroll") for (int kk = 0; kk < 2; ++kk)                                     \
    _Pragma("unroll") for (int fm = 0; fm < 4; ++fm)                                     \
    _Pragma("unroll") for (int j = 0; j < 2; ++j)                                       \
      acc[(Msub) * 4 + fm][j] = __builtin_amdgcn_mfma_f32_16x16x32_bf16(                 \
          af[kk][fm], bb[kk][j], acc[(Msub) * 4 + fm][j], 0, 0, 0);                      \
    __builtin_amdgcn_s_setprio(0);                                                       \
  } while (0)

__global__ __launch_bounds__(512, 1) void gemm256x128_kernel(
    const unsigned short* __restrict__ Ap, const unsigned short* __restrict__ Bp,
    float* __restrict__ C, int K, int N) {
  __shared__ unsigned short S[49152];  // 96 KiB
  const int tid = threadIdx.x;
  const int lane = tid & 63, w = tid >> 6;
  const int l15 = lane & 15, lg = lane >> 4;
  const int nwgx = gridDim.x;  // N/128
  const int nwg = nwgx * gridDim.y;
  int lid = blockIdx.x + nwgx * blockIdx.y;
  lid = (lid & 7) * (nwg >> 3) + (lid >> 3);
  const int m0 = (lid / nwgx) * 256, n0 = (lid % nwgx) * 128;
  const int ah = w >> 2;
  const int wn = (w & 3) * 32;
  const int NT = K >> 6;
  const int Kd = K;
  const int sr = tid >> 3;
  const int sc = ((tid & 7) ^ (sr & 7)) << 3;

  f32x4 acc[8][2];
#pragma unroll
  for (int i = 0; i < 8; ++i)
#pragma unroll
    for (int j = 0; j < 2; ++j)
#pragma unroll
      for (int c = 0; c < 4; ++c) acc[i][j][c] = 0.f;

  SB2(0); SA2(0, 0); SA2(0, 1); SB2(1); SA2(1, 0);
  asm volatile("s_waitcnt vmcnt(4)" ::: "memory");
  __builtin_amdgcn_s_barrier();

  short8 af[2][4], b0[2][2], b1[2][2];

  for (int t = 0; t < NT; t += 2) {
    const bool nl = (t + 2 < NT);
    RDA2(t, 0); RDB2(b0, t);
    SA2(t + 1, 1);
    BAR();
    MM2(0, b0);
    BAR();
    RDA2(t, 1);
    if (nl) {
      SB2(t + 2); SA2(t + 2, 0);
      asm volatile("s_waitcnt vmcnt(4)" ::: "memory");
    } else {
      asm volatile("s_waitcnt vmcnt(0)" ::: "memory");
    }
    BAR();
    MM2(1, b0);
    BAR();
    RDA2(t + 1, 0); RDB2(b1, t + 1);
    if (nl) SA2(t + 2, 1);
    BAR();
    MM2(0, b1);
    BAR();
    RDA2(t + 1, 1);
    if (nl) {
      SB2(t + 3); SA2(t + 3, 0);
      asm volatile("s_waitcnt vmcnt(4)" ::: "memory");
    }
    BAR();
    MM2(1, b1);
    BAR();
  }

#pragma unroll
  for (int fm8 = 0; fm8 < 8; ++fm8)
#pragma unroll
    for (int j = 0; j < 2; ++j) {
      const size_t base =
          (size_t)(m0 + ah * 128 + (fm8 >> 2) * 64 + (fm8 & 3) * 16 + lg * 4) * N +
          (n0 + wn + j * 16 + l15);
#pragma unroll
      for (int r = 0; r < 4; ++r) C[base + (size_t)r * N] = acc[fm8][j][r];
    }
}

// -------------------- bf16 MFMA flash attention (causal, GQA 4:1) -----------
__global__ __launch_bounds__(256) void attn_mfma_kernel(
    const unsigned short* __restrict__ qb, const unsigned short* __restrict__ kb,
    const unsigned short* __restrict__ vt, unsigned short* __restrict__ attnb) {
  int lid = blockIdx.x + 8 * (blockIdx.y + 32 * blockIdx.z);  // 1024 blocks
  lid = (lid & 7) * 128 + (lid >> 3);                         // bijective chunk
  const int bx = lid & 7, h = (lid >> 3) & 31, b = lid >> 8;
  const int kvh = h >> 2;
  __shared__ unsigned short S[20480];  // 40 KiB
  const int tid = threadIdx.x, lane = tid & 63, w = tid >> 6;
  const int l15 = lane & 15, lg = lane >> 4;
  const int rowbase = w * 16 + lg * 4;

  const int gi0 = w * 64 + lane;
  const int r0 = gi0 >> 3, g0 = (gi0 & 7) ^ (r0 & 7);
  const int gi1 = (4 + w) * 64 + lane;
  const int r1 = gi1 >> 3, g1 = (gi1 & 7) ^ (r1 & 7);

  const unsigned short* kbase = kb + (size_t)b * 1024 * 512 + kvh * 64;
  const unsigned short* vbase = vt + (size_t)(b * 8 + kvh) * 64 * 1024;

#define STAGE_KV(kOff, vOff, jj)                                                    \
  do {                                                                              \
    __builtin_amdgcn_global_load_lds(AS1C(kbase + ((jj) * 64 + r0) * 512 + g0 * 8), \
                                     AS3(&S[(kOff) + w * 512]), 16, 0, 0);          \
    __builtin_amdgcn_global_load_lds(AS1C(kbase + ((jj) * 64 + r1) * 512 + g1 * 8), \
                                     AS3(&S[(kOff) + (4 + w) * 512]), 16, 0, 0);    \
    __builtin_amdgcn_global_load_lds(AS1C(vbase + r0 * 1024 + (jj) * 64 + g0 * 8),  \
                                     AS3(&S[(vOff) + w * 512]), 16, 0, 0);          \
    __builtin_amdgcn_global_load_lds(AS1C(vbase + r1 * 1024 + (jj) * 64 + g1 * 8),  \
                                     AS3(&S[(vOff) + (4 + w) * 512]), 16, 0, 0);    \
  } while (0)

#define STAGE_Q(qt)                                                                     \
  do {                                                                                  \
    const size_t qr_ = (size_t)b * 1024 + (qt) * 64;                                    \
    __builtin_amdgcn_global_load_lds(AS1C(qb + (qr_ + r0) * 2048 + h * 64 + g0 * 8),    \
                                     AS3(&S[w * 512]), 16, 0, 0);                       \
    __builtin_amdgcn_global_load_lds(AS1C(qb + (qr_ + r1) * 2048 + h * 64 + g1 * 8),    \
                                     AS3(&S[(4 + w) * 512]), 16, 0, 0);                 \
  } while (0)

  const int qts0 = bx, qts1 = 15 - bx;

  short8 ones;
#pragma unroll
  for (int i = 0; i < 8; ++i) ones[i] = (short)0x3F80;  // bf16 1.0

  STAGE_Q(qts0);
  STAGE_KV(4096, 12288, 0);
  __syncthreads();

  int g = 0;
  for (int sub = 0; sub < 2; ++sub) {
    const int qtc = sub ? qts1 : qts0;
    const size_t qrow0 = (size_t)b * 1024 + qtc * 64;

    short8 qf[2];
#pragma unroll
    for (int kk = 0; kk < 2; ++kk) {
      const int r = w * 16 + l15;
      const int gq = ((kk << 2) | lg) ^ (r & 7);
      qf[kk] = *(const short8*)&S[r * 64 + gq * 8];
    }

    f32x4 oa[4], oe;
#pragma unroll
    for (int r = 0; r < 4; ++r) oe[r] = 0.f;
#pragma unroll
    for (int fd = 0; fd < 4; ++fd)
#pragma unroll
      for (int r = 0; r < 4; ++r) oa[fd][r] = 0.f;

    for (int j = 0; j <= qtc; ++j, ++g) {
      const int cur = g & 1;
      const int kOff = 4096 + cur * 4096;
      const int vOff = 12288 + cur * 4096;
      if (g < 16) {
        const int nj = (g + 1 <= qts0) ? g + 1 : g - qts0;
        STAGE_KV(4096 + (cur ^ 1) * 4096, 12288 + (cur ^ 1) * 4096, nj);
      }

      f32x4 sa[4];
#pragma unroll
      for (int fn = 0; fn < 4; ++fn)
#pragma unroll
        for (int r = 0; r < 4; ++r) sa[fn][r] = 0.f;
#pragma unroll
      for (int kk = 0; kk < 2; ++kk) {
        short8 kf[4];
#pragma unroll
        for (int fn = 0; fn < 4; ++fn) {
          const int rkv = fn * 16 + l15;
          const int gk = ((kk << 2) | lg) ^ (rkv & 7);
          kf[fn] = *(const short8*)&S[kOff + rkv * 64 + gk * 8];
        }
        __builtin_amdgcn_s_setprio(1);
#pragma unroll
        for (int fn = 0; fn < 4; ++fn)
          sa[fn] = __builtin_amdgcn_mfma_f32_16x16x32_bf16(qf[kk], kf[fn], sa[fn], 0, 0, 0);
        __builtin_amdgcn_s_setprio(0);
      }

      if (j == qtc) {
#pragma unroll
        for (int r = 0; r < 4; ++r) {
          const int row = rowbase + r;
#pragma unroll
          for (int fn = 0; fn < 4; ++fn)
            if ((fn * 16 + l15) > row) sa[fn][r] = -INFINITY;
        }
      }
#pragma unroll
      for (int fn = 0; fn < 4; ++fn)
#pragma unroll
        for (int r = 0; r < 4; ++r) sa[fn][r] = ex2(sa[fn][r]);

#pragma unroll
      for (int r = 0; r < 4; ++r) {
        const int prow = rowbase + r;
#pragma unroll
        for (int fn = 0; fn < 4; ++fn) {
          const int col = fn * 16 + l15;
          const int gp = (col >> 3) ^ (prow & 7);
          S[prow * 64 + gp * 8 + (col & 7)] = bfc(sa[fn][r]);
        }
      }

#pragma unroll
      for (int kk = 0; kk < 2; ++kk) {
        const int rp = w * 16 + l15;
        const int gp = ((kk << 2) | lg) ^ (rp & 7);
        const short8 pf = *(const short8*)&S[rp * 64 + gp * 8];
        short8 vf[4];
#pragma unroll
        for (int fd = 0; fd < 4; ++fd) {
          const int rd = fd * 16 + l15;
          const int gv = ((kk << 2) | lg) ^ (rd & 7);
          vf[fd] = *(const short8*)&S[vOff + rd * 64 + gv * 8];
        }
        __builtin_amdgcn_s_setprio(1);
#pragma unroll
        for (int fd = 0; fd < 4; ++fd)
          oa[fd] = __builtin_amdgcn_mfma_f32_16x16x32_bf16(pf, vf[fd], oa[fd], 0, 0, 0);
        oe = __builtin_amdgcn_mfma_f32_16x16x32_bf16(pf, ones, oe, 0, 0, 0);
        __builtin_amdgcn_s_setprio(0);
      }

      __syncthreads();
    }

#pragma unroll
    for (int r = 0; r < 4; ++r) {
      const float inv = 1.0f / oe[r];
      const size_t row = qrow0 + rowbase + r;
#pragma unroll
      for (int fd = 0; fd < 4; ++fd)
        attnb[row * 2048 + h * 64 + fd * 16 + l15] = f2bf(oa[fd][r] * inv);
    }

    if (sub == 0) {
      STAGE_Q(qts1);
      __syncthreads();
    }
  }
#undef STAGE_KV
#undef STAGE_Q
}

// ---------------------------------------------------------------------------
extern "C" void kernel_launch(void* const* d_in, const int* in_sizes, int n_in,
                              void* d_out, int out_size, void* d_ws, size_t ws_size,
                              hipStream_t stream) {
  (void)in_sizes; (void)n_in; (void)out_size; (void)ws_size;
  const float* x  = (const float*)d_in[0];
  const float* Wq = (const float*)d_in[1];
  const float* Wk = (const float*)d_in[2];
  const float* Wv = (const float*)d_in[3];
  const float* Wp = (const float*)d_in[4];

  char* w = (char*)d_ws;
  unsigned short* xb    = (unsigned short*)(w);
  unsigned short* Wt    = (unsigned short*)(w + 16777216);
  unsigned short* Wpt   = (unsigned short*)(w + 29360128);
  float*          qkf   = (float*)(w + 37748736);
  unsigned short* vtb   = (unsigned short*)(w + 79691776);
  unsigned short* attnb = (unsigned short*)(w + 83886080);
  float2*         rtab  = (float2*)(w + 100663296);
  unsigned short* qb    = (unsigned short*)(w);             // overlays xb
  unsigned short* kbuf  = (unsigned short*)(w + 16777216);  // overlays Wt
  float* out = (float*)d_out;

  rope_tab_kernel<<<128, 256, 0, stream>>>(rtab);
  cvt_bf16_kernel<<<8192, 256, 0, stream>>>(x, xb, 2097152);
  transpose_w_kernel<<<dim3(64, 64, 4), 256, 0, stream>>>(Wq, Wk, Wv, Wp, Wt, Wpt);

  // QKV projection: 256x192 tiles, triple-buffered B, 256 blocks
  gemm256x192_qkv_kernel<<<dim3(16, 16), 512, 0, stream>>>(xb, Wt, qkf, vtb);
  // wide table-based RoPE: qkf f32 -> qb/kb bf16
  rope_cvt2_kernel<<<5120, 256, 0, stream>>>(rtab, qkf, qb, kbuf);
  // flash attention
  attn_mfma_kernel<<<dim3(8, 32, 4), 256, 0, stream>>>(qb, kbuf, vtb, attnb);
  // output projection: 256x128 tiles -> 256 blocks, full CU fill
  gemm256x128_kernel<<<dim3(16, 16), 512, 0, stream>>>(attnb, Wpt, out, 2048, 2048);
}

// Round 20
// 162.277 us; speedup vs baseline: 1.0251x; 1.0251x over previous
//
#include <hip/hip_runtime.h>
#include <hip/hip_bf16.h>

// ---------------------------------------------------------------------------
// SelfAttention fused pipeline for MI355X (gfx950)
//   QKV GEMM 256x192 6-phase dbuf-B (256 blocks full fill); Q/K epilogue =
//   packed ushort2 bf16 stores (lane-pair shfl), V^T bf16; in-place table
//   RoPE on bf16; bf16 MFMA attention (no-max log2 softmax); projection
//   GEMM 256x128 (256 blocks full fill).
// ---------------------------------------------------------------------------

typedef __attribute__((ext_vector_type(4))) float f32x4;
typedef __attribute__((ext_vector_type(8))) short short8;

#define AS1C(p) ((const __attribute__((address_space(1))) void*)(p))
#define AS3(p)  ((__attribute__((address_space(3))) void*)(p))

__device__ __forceinline__ unsigned short f2bf(float f) {
  union { float f; unsigned int u; } x; x.f = f;
  unsigned int r = x.u + 0x7FFFu + ((x.u >> 16) & 1u);
  return (unsigned short)(r >> 16);
}

__device__ __forceinline__ unsigned short bfc(float f) {
  return __bfloat16_as_ushort(__float2bfloat16(f));
}

__device__ __forceinline__ float bf2f(unsigned short u) {
  union { float f; unsigned int v; } x; x.v = ((unsigned int)u) << 16;
  return x.f;
}

__device__ __forceinline__ float ex2(float x) {
  return __builtin_amdgcn_exp2f(x);
}

// -------------------- RoPE table: tab[t*32+i] = (cos, sin) ------------------
__global__ void rope_tab_kernel(float2* __restrict__ tab) {
  const int idx = blockIdx.x * 256 + threadIdx.x;  // 32768
  const int t = idx >> 5, i = idx & 31;
  const float invf = exp2f(-(float)i * 0.41524101186092029f);
  float sv, cv;
  __sincosf((float)t * invf, &sv, &cv);
  tab[idx] = make_float2(cv, sv);
}

// -------------------- x : f32 -> bf16 (vectorized) -------------------------
__global__ void cvt_bf16_kernel(const float* __restrict__ src,
                                unsigned short* __restrict__ dst, int n4) {
  int i = blockIdx.x * blockDim.x + threadIdx.x;
  if (i >= n4) return;
  const f32x4 v = *(const f32x4*)(src + (size_t)i * 4);
  ushort4 u = make_ushort4(f2bf(v[0]), f2bf(v[1]), f2bf(v[2]), f2bf(v[3]));
  *(ushort4*)(dst + (size_t)i * 4) = u;
}

// -- fused W transpose: z=0 Wq(*qs) z=1 Wk z=2 Wv -> Wt; z=3 Wp -> Wpt -------
__global__ void transpose_w_kernel(const float* __restrict__ Wq,
                                   const float* __restrict__ Wk,
                                   const float* __restrict__ Wv,
                                   const float* __restrict__ Wp,
                                   unsigned short* __restrict__ Wt,
                                   unsigned short* __restrict__ Wpt) {
  __shared__ float tile[32][33];
  const int z = blockIdx.z;
  const float* src;
  unsigned short* dst;
  int N, rowOff;
  float scale = 1.0f;
  if (z == 0)      { src = Wq; dst = Wt;  N = 2048; rowOff = 0;    scale = 0.18033688011112042f; }
  else if (z == 1) { src = Wk; dst = Wt;  N = 512;  rowOff = 2048; }
  else if (z == 2) { src = Wv; dst = Wt;  N = 512;  rowOff = 2560; }
  else             { src = Wp; dst = Wpt; N = 2048; rowOff = 0;    }
  const int n0 = blockIdx.x * 32, k0 = blockIdx.y * 32;
  if (n0 >= N) return;
  const int tx = threadIdx.x & 31, ty = threadIdx.x >> 5;
#pragma unroll
  for (int i = ty; i < 32; i += 8)
    tile[i][tx] = src[(size_t)(k0 + i) * N + (n0 + tx)];
  __syncthreads();
#pragma unroll
  for (int i = ty; i < 32; i += 8)
    dst[(size_t)(rowOff + n0 + i) * 2048 + (k0 + tx)] = f2bf(tile[tx][i] * scale);
}

// ---- wide RoPE (in-place, bf16): 8 elems/thread, table-based ---------------
__global__ void rope_bf16_kernel(const float2* __restrict__ tab,
                                 unsigned short* __restrict__ qb,
                                 unsigned short* __restrict__ kb) {
  const int idx = blockIdx.x * 256 + threadIdx.x;  // 4096*320
  const int m = idx / 320;
  const int p = idx - m * 320;
  const int t = m & 1023;
  unsigned short* base;
  int col;
  if (p < 256) { base = qb + (size_t)m * 2048; col = p * 8; }
  else         { base = kb + (size_t)m * 512;  col = (p - 256) * 8; }
  const int i0 = (col & 63) >> 1;
  short8 v = *(short8*)(base + col);
  short8 o;
#pragma unroll
  for (int j = 0; j < 4; ++j) {
    const float2 cs = tab[t * 32 + i0 + j];
    const float x1 = bf2f((unsigned short)v[2 * j]);
    const float x2 = bf2f((unsigned short)v[2 * j + 1]);
    o[2 * j]     = (short)bfc(x1 * cs.x - x2 * cs.y);
    o[2 * j + 1] = (short)bfc(x2 * cs.x + x1 * cs.y);
  }
  *(short8*)(base + col) = o;
}

#define BAR() __builtin_amdgcn_s_barrier()

// =========== 256x192 QKV GEMM: 256 blocks, 8 waves = 4M x 2N ================
// LDS 112 KiB (shorts): A buf(tile&1) @ tile<<14 (256x64 each); B buf(tile&1)
// @ 32768 + (tile&1)*12288 (192x64 each). Granule-XOR swizzle both-sides;
// XCD-chunked block swizzle. 6 phases / 2 K-tiles (R18 schedule, dbuf B,
// gates vmcnt(5) @P3/P6). Q/K epilogue: packed ushort2 bf16 (lane-pair shfl).
#define SA3(tile, half)                                                                  \
  do {                                                                                   \
    const unsigned short* p_ = Ap + (size_t)(m0 + (half) * 128 + sr) * 2048 + (tile) * 64 + sc; \
    const int d_ = (((tile) & 1) << 14) + ((half) << 13) + tid * 8;                      \
    __builtin_amdgcn_global_load_lds(AS1C(p_), AS3(&S[d_]), 16, 0, 0);                   \
    __builtin_amdgcn_global_load_lds(AS1C(p_ + (size_t)64 * 2048), AS3(&S[d_ + 4096]), 16, 0, 0); \
  } while (0)

#define SB3(tile, u)                                                                     \
  do {                                                                                   \
    const unsigned short* p_ = Bp + (size_t)(n0 + (u) * 64 + sr) * 2048 + (tile) * 64 + sc; \
    const int d_ = 32768 + ((tile) & 1) * 12288 + (u) * 4096 + tid * 8;                  \
    __builtin_amdgcn_global_load_lds(AS1C(p_), AS3(&S[d_]), 16, 0, 0);                   \
  } while (0)

#define RDA3(tile)                                                                       \
  _Pragma("unroll") for (int kk = 0; kk < 2; ++kk)                                       \
  _Pragma("unroll") for (int fm = 0; fm < 4; ++fm) {                                     \
    const int r_ = mg * 64 + fm * 16 + l15;                                              \
    af[kk][fm] = *(const short8*)&S[(((tile) & 1) << 14) + r_ * 64 +                     \
                                    (((kk << 2) | lg) ^ (r_ & 7)) * 8];                  \
  }

#define RDB3(tile, p)                                                                    \
  _Pragma("unroll") for (int kk = 0; kk < 2; ++kk)                                       \
  _Pragma("unroll") for (int jj = 0; jj < 2; ++jj) {                                     \
    const int r_ = ng * 96 + ((p) * 2 + jj) * 16 + l15;                                  \
    bf[kk][jj] = *(const short8*)&S[32768 + ((tile) & 1) * 12288 + r_ * 64 +             \
                                    (((kk << 2) | lg) ^ (r_ & 7)) * 8];                  \
  }

#define MM3(p)                                                                           \
  do {                                                                                   \
    __builtin_amdgcn_s_setprio(1);                                                       \
    _Pragma("unroll") for (int kk = 0; kk < 2; ++kk)                                     \
    _Pragma("unroll") for (int fm = 0; fm < 4; ++fm)                                     \
    _Pragma("unroll") for (int jj = 0; jj < 2; ++jj)                                     \
      acc[fm][(p) * 2 + jj] = __builtin_amdgcn_mfma_f32_16x16x32_bf16(                   \
          af[kk][fm], bf[kk][jj], acc[fm][(p) * 2 + jj], 0, 0, 0);                       \
    __builtin_amdgcn_s_setprio(0);                                                       \
  } while (0)

__global__ __launch_bounds__(512, 1) void gemm256x192_qkv_kernel(
    const unsigned short* __restrict__ Ap, const unsigned short* __restrict__ Bp,
    unsigned short* __restrict__ qb, unsigned short* __restrict__ kb,
    unsigned short* __restrict__ vt) {
  __shared__ unsigned short S[57344];  // 112 KiB
  const int tid = threadIdx.x;
  const int lane = tid & 63, w = tid >> 6;
  const int l15 = lane & 15, lg = lane >> 4;
  int lid = blockIdx.x + 16 * blockIdx.y;          // 256 blocks
  lid = (lid & 7) * 32 + (lid >> 3);               // bijective XCD chunk
  const int m0 = (lid >> 4) * 256, n0 = (lid & 15) * 192;
  const int mg = w >> 1;   // 4 M-groups of 64 rows
  const int ng = w & 1;    // 2 N-groups of 96 cols
  const int sr = tid >> 3;
  const int sc = ((tid & 7) ^ (sr & 7)) << 3;
  const int NT = 32;       // K=2048

  f32x4 acc[4][6];
#pragma unroll
  for (int i = 0; i < 4; ++i)
#pragma unroll
    for (int j = 0; j < 6; ++j)
#pragma unroll
      for (int c = 0; c < 4; ++c) acc[i][j][c] = 0.f;

  // prologue: A(0), B(0) full; A(1), B(1)u0 (B(1)u1,u2 deferred to P1)
  SA3(0, 0); SA3(0, 1); SB3(0, 0); SB3(0, 1); SB3(0, 2);
  SA3(1, 0); SA3(1, 1); SB3(1, 0);
  asm volatile("s_waitcnt vmcnt(5)" ::: "memory");  // tile-0 data retired
  BAR();

  short8 af[2][4], bf[2][2];

  for (int t = 0; t < NT; t += 2) {
    const bool nl = (t + 2 < NT);
    // P1: read A(t), B(t)p0; stage B(t+1)u1,u2 (regions freed prev-P6)
    RDA3(t); RDB3(t, 0);
    SB3(t + 1, 1); SB3(t + 1, 2);
    BAR();
    MM3(0);
    BAR();
    // P2: read B(t)p1; stage A(t+2)h0 (A(t) fully read in P1)
    RDB3(t, 1);
    if (nl) SA3(t + 2, 0);
    BAR();
    MM3(1);
    BAR();
    // P3: read B(t)p2; stage A(t+2)h1, B(t+2)u0; gate: P1's loads retired
    RDB3(t, 2);
    if (nl) {
      SA3(t + 2, 1); SB3(t + 2, 0);
      asm volatile("s_waitcnt vmcnt(5)" ::: "memory");
    } else {
      asm volatile("s_waitcnt vmcnt(0)" ::: "memory");
    }
    BAR();
    MM3(2);
    BAR();
    // P4: read A(t+1), B(t+1)p0; stage B(t+2)u1,u2 (freed after P3)
    RDA3(t + 1); RDB3(t + 1, 0);
    if (nl) { SB3(t + 2, 1); SB3(t + 2, 2); }
    BAR();
    MM3(0);
    BAR();
    // P5: read B(t+1)p1; stage A(t+3)h0 (A(t+1) fully read in P4)
    RDB3(t + 1, 1);
    if (nl) SA3(t + 3, 0);
    BAR();
    MM3(1);
    BAR();
    // P6: read B(t+1)p2; stage A(t+3)h1, B(t+3)u0; gate: t+2 loads retired
    RDB3(t + 1, 2);
    if (nl) {
      SA3(t + 3, 1); SB3(t + 3, 0);
      asm volatile("s_waitcnt vmcnt(5)" ::: "memory");
    }
    BAR();
    MM3(2);
    BAR();
  }

  // epilogue: per-fragment region branch (boundaries are 16-col aligned)
#pragma unroll
  for (int fn = 0; fn < 6; ++fn) {
    const int col16 = n0 + ng * 96 + fn * 16;
    if (col16 < 2560) {
      // Q/K: packed ushort2 bf16 stores (even l15 lane writes the pair)
      const bool isQ = (col16 < 2048);
      unsigned short* dstb = isQ ? qb : kb;
      const int ld = isQ ? 2048 : 512;
      const int coff = (isQ ? col16 : col16 - 2048) + l15;
#pragma unroll
      for (int fm = 0; fm < 4; ++fm) {
        const int row = m0 + mg * 64 + fm * 16 + lg * 4;
#pragma unroll
        for (int r = 0; r < 4; ++r) {
          const float v = acc[fm][fn][r];
          const float pp = __shfl_xor(v, 1);  // partner col's value
          if (!(l15 & 1))
            *(ushort2*)&dstb[(size_t)(row + r) * ld + coff] =
                make_ushort2(bfc(v), bfc(pp));
        }
      }
    } else {
      // V: packed transposed bf16 store
      const int dz = (col16 - 2560) >> 6;
      const int d = ((col16 - 2560) & 63) + l15;
#pragma unroll
      for (int fm = 0; fm < 4; ++fm) {
        const int row = m0 + mg * 64 + fm * 16 + lg * 4;
        const int z = (row >> 10) * 8 + dz;
        const int t0 = row & 1023;
        ushort4 u = make_ushort4(bfc(acc[fm][fn][0]), bfc(acc[fm][fn][1]),
                                 bfc(acc[fm][fn][2]), bfc(acc[fm][fn][3]));
        *(ushort4*)&vt[(size_t)z * 65536 + d * 1024 + t0] = u;
      }
    }
  }
}

// ============ 256x128 GEMM (projection): 8 waves 2Mx4N (32-col strips) ======
#define SA2(tile, half)                                                                  \
  do {                                                                                   \
    const unsigned short* p_ = Ap + (size_t)(m0 + (half) * 128 + sr) * Kd + (tile) * 64 + sc; \
    const int d_ = (((tile) & 1) << 14) + ((half) << 13) + tid * 8;                      \
    __builtin_amdgcn_global_load_lds(AS1C(p_), AS3(&S[d_]), 16, 0, 0);                   \
    __builtin_amdgcn_global_load_lds(AS1C(p_ + (size_t)64 * Kd), AS3(&S[d_ + 4096]), 16, 0, 0); \
  } while (0)

#define SB2(tile)                                                                        \
  do {                                                                                   \
    const unsigned short* p_ = Bp + (size_t)(n0 + sr) * Kd + (tile) * 64 + sc;           \
    const int d_ = 32768 + (((tile) & 1) << 13) + tid * 8;                               \
    __builtin_amdgcn_global_load_lds(AS1C(p_), AS3(&S[d_]), 16, 0, 0);                   \
    __builtin_amdgcn_global_load_lds(AS1C(p_ + (size_t)64 * Kd), AS3(&S[d_ + 4096]), 16, 0, 0); \
  } while (0)

#define RDA2(tile, Msub)                                                                 \
  _Pragma("unroll") for (int kk = 0; kk < 2; ++kk)                                       \
  _Pragma("unroll") for (int fm = 0; fm < 4; ++fm) {                                     \
    const int r_ = (Msub) * 64 + fm * 16 + l15;                                          \
    af[kk][fm] = *(const short8*)&S[(((tile) & 1) << 14) + (ah << 13) + r_ * 64 +        \
                                    (((kk << 2) | lg) ^ (r_ & 7)) * 8];                  \
  }

#define RDB2(dst, tile)                                                                  \
  _Pragma("unroll") for (int kk = 0; kk < 2; ++kk)                                       \
  _Pragma("unroll") for (int j = 0; j < 2; ++j) {                                        \
    const int r_ = wn + j * 16 + l15;                                                    \
    dst[kk][j] = *(const short8*)&S[32768 + (((tile) & 1) << 13) + r_ * 64 +             \
                                    (((kk << 2) | lg) ^ (r_ & 7)) * 8];                  \
  }

#define MM2(Msub, bb)                                                                    \
  do {                                                                                   \
    __builtin_amdgcn_s_setprio(1);                                                       \
    _Pragma("unroll") for (int kk = 0; kk < 2; ++kk)                                     \
    _Pragma("unroll") for (int fm = 0; fm < 4; ++fm)                                     \
    _Pragma("unroll") for (int j = 0; j < 2; ++j)                                        \
      acc[(Msub) * 4 + fm][j] = __builtin_amdgcn_mfma_f32_16x16x32_bf16(                 \
          af[kk][fm], bb[kk][j], acc[(Msub) * 4 + fm][j], 0, 0, 0);                      \
    __builtin_amdgcn_s_setprio(0);                                                       \
  } while (0)

__global__ __launch_bounds__(512, 1) void gemm256x128_kernel(
    const unsigned short* __restrict__ Ap, const unsigned short* __restrict__ Bp,
    float* __restrict__ C, int K, int N) {
  __shared__ unsigned short S[49152];  // 96 KiB
  const int tid = threadIdx.x;
  const int lane = tid & 63, w = tid >> 6;
  const int l15 = lane & 15, lg = lane >> 4;
  const int nwgx = gridDim.x;  // N/128
  const int nwg = nwgx * gridDim.y;
  int lid = blockIdx.x + nwgx * blockIdx.y;
  lid = (lid & 7) * (nwg >> 3) + (lid >> 3);
  const int m0 = (lid / nwgx) * 256, n0 = (lid % nwgx) * 128;
  const int ah = w >> 2;
  const int wn = (w & 3) * 32;
  const int NT = K >> 6;
  const int Kd = K;
  const int sr = tid >> 3;
  const int sc = ((tid & 7) ^ (sr & 7)) << 3;

  f32x4 acc[8][2];
#pragma unroll
  for (int i = 0; i < 8; ++i)
#pragma unroll
    for (int j = 0; j < 2; ++j)
#pragma unroll
      for (int c = 0; c < 4; ++c) acc[i][j][c] = 0.f;

  SB2(0); SA2(0, 0); SA2(0, 1); SB2(1); SA2(1, 0);
  asm volatile("s_waitcnt vmcnt(4)" ::: "memory");
  __builtin_amdgcn_s_barrier();

  short8 af[2][4], b0[2][2], b1[2][2];

  for (int t = 0; t < NT; t += 2) {
    const bool nl = (t + 2 < NT);
    RDA2(t, 0); RDB2(b0, t);
    SA2(t + 1, 1);
    BAR();
    MM2(0, b0);
    BAR();
    RDA2(t, 1);
    if (nl) {
      SB2(t + 2); SA2(t + 2, 0);
      asm volatile("s_waitcnt vmcnt(4)" ::: "memory");
    } else {
      asm volatile("s_waitcnt vmcnt(0)" ::: "memory");
    }
    BAR();
    MM2(1, b0);
    BAR();
    RDA2(t + 1, 0); RDB2(b1, t + 1);
    if (nl) SA2(t + 2, 1);
    BAR();
    MM2(0, b1);
    BAR();
    RDA2(t + 1, 1);
    if (nl) {
      SB2(t + 3); SA2(t + 3, 0);
      asm volatile("s_waitcnt vmcnt(4)" ::: "memory");
    }
    BAR();
    MM2(1, b1);
    BAR();
  }

#pragma unroll
  for (int fm8 = 0; fm8 < 8; ++fm8)
#pragma unroll
    for (int j = 0; j < 2; ++j) {
      const size_t base =
          (size_t)(m0 + ah * 128 + (fm8 >> 2) * 64 + (fm8 & 3) * 16 + lg * 4) * N +
          (n0 + wn + j * 16 + l15);
#pragma unroll
      for (int r = 0; r < 4; ++r) C[base + (size_t)r * N] = acc[fm8][j][r];
    }
}

// -------------------- bf16 MFMA flash attention (causal, GQA 4:1) -----------
__global__ __launch_bounds__(256) void attn_mfma_kernel(
    const unsigned short* __restrict__ qb, const unsigned short* __restrict__ kb,
    const unsigned short* __restrict__ vt, unsigned short* __restrict__ attnb) {
  int lid = blockIdx.x + 8 * (blockIdx.y + 32 * blockIdx.z);  // 1024 blocks
  lid = (lid & 7) * 128 + (lid >> 3);                         // bijective chunk
  const int bx = lid & 7, h = (lid >> 3) & 31, b = lid >> 8;
  const int kvh = h >> 2;
  __shared__ unsigned short S[20480];  // 40 KiB
  const int tid = threadIdx.x, lane = tid & 63, w = tid >> 6;
  const int l15 = lane & 15, lg = lane >> 4;
  const int rowbase = w * 16 + lg * 4;

  const int gi0 = w * 64 + lane;
  const int r0 = gi0 >> 3, g0 = (gi0 & 7) ^ (r0 & 7);
  const int gi1 = (4 + w) * 64 + lane;
  const int r1 = gi1 >> 3, g1 = (gi1 & 7) ^ (r1 & 7);

  const unsigned short* kbase = kb + (size_t)b * 1024 * 512 + kvh * 64;
  const unsigned short* vbase = vt + (size_t)(b * 8 + kvh) * 64 * 1024;

#define STAGE_KV(kOff, vOff, jj)                                                    \
  do {                                                                              \
    __builtin_amdgcn_global_load_lds(AS1C(kbase + ((jj) * 64 + r0) * 512 + g0 * 8), \
                                     AS3(&S[(kOff) + w * 512]), 16, 0, 0);          \
    __builtin_amdgcn_global_load_lds(AS1C(kbase + ((jj) * 64 + r1) * 512 + g1 * 8), \
                                     AS3(&S[(kOff) + (4 + w) * 512]), 16, 0, 0);    \
    __builtin_amdgcn_global_load_lds(AS1C(vbase + r0 * 1024 + (jj) * 64 + g0 * 8),  \
                                     AS3(&S[(vOff) + w * 512]), 16, 0, 0);          \
    __builtin_amdgcn_global_load_lds(AS1C(vbase + r1 * 1024 + (jj) * 64 + g1 * 8),  \
                                     AS3(&S[(vOff) + (4 + w) * 512]), 16, 0, 0);    \
  } while (0)

#define STAGE_Q(qt)                                                                     \
  do {                                                                                  \
    const size_t qr_ = (size_t)b * 1024 + (qt) * 64;                                    \
    __builtin_amdgcn_global_load_lds(AS1C(qb + (qr_ + r0) * 2048 + h * 64 + g0 * 8),    \
                                     AS3(&S[w * 512]), 16, 0, 0);                       \
    __builtin_amdgcn_global_load_lds(AS1C(qb + (qr_ + r1) * 2048 + h * 64 + g1 * 8),    \
                                     AS3(&S[(4 + w) * 512]), 16, 0, 0);                 \
  } while (0)

  const int qts0 = bx, qts1 = 15 - bx;

  short8 ones;
#pragma unroll
  for (int i = 0; i < 8; ++i) ones[i] = (short)0x3F80;  // bf16 1.0

  STAGE_Q(qts0);
  STAGE_KV(4096, 12288, 0);
  __syncthreads();

  int g = 0;
  for (int sub = 0; sub < 2; ++sub) {
    const int qtc = sub ? qts1 : qts0;
    const size_t qrow0 = (size_t)b * 1024 + qtc * 64;

    short8 qf[2];
#pragma unroll
    for (int kk = 0; kk < 2; ++kk) {
      const int r = w * 16 + l15;
      const int gq = ((kk << 2) | lg) ^ (r & 7);
      qf[kk] = *(const short8*)&S[r * 64 + gq * 8];
    }

    f32x4 oa[4], oe;
#pragma unroll
    for (int r = 0; r < 4; ++r) oe[r] = 0.f;
#pragma unroll
    for (int fd = 0; fd < 4; ++fd)
#pragma unroll
      for (int r = 0; r < 4; ++r) oa[fd][r] = 0.f;

    for (int j = 0; j <= qtc; ++j, ++g) {
      const int cur = g & 1;
      const int kOff = 4096 + cur * 4096;
      const int vOff = 12288 + cur * 4096;
      if (g < 16) {
        const int nj = (g + 1 <= qts0) ? g + 1 : g - qts0;
        STAGE_KV(4096 + (cur ^ 1) * 4096, 12288 + (cur ^ 1) * 4096, nj);
      }

      f32x4 sa[4];
#pragma unroll
      for (int fn = 0; fn < 4; ++fn)
#pragma unroll
        for (int r = 0; r < 4; ++r) sa[fn][r] = 0.f;
#pragma unroll
      for (int kk = 0; kk < 2; ++kk) {
        short8 kf[4];
#pragma unroll
        for (int fn = 0; fn < 4; ++fn) {
          const int rkv = fn * 16 + l15;
          const int gk = ((kk << 2) | lg) ^ (rkv & 7);
          kf[fn] = *(const short8*)&S[kOff + rkv * 64 + gk * 8];
        }
        __builtin_amdgcn_s_setprio(1);
#pragma unroll
        for (int fn = 0; fn < 4; ++fn)
          sa[fn] = __builtin_amdgcn_mfma_f32_16x16x32_bf16(qf[kk], kf[fn], sa[fn], 0, 0, 0);
        __builtin_amdgcn_s_setprio(0);
      }

      if (j == qtc) {
#pragma unroll
        for (int r = 0; r < 4; ++r) {
          const int row = rowbase + r;
#pragma unroll
          for (int fn = 0; fn < 4; ++fn)
            if ((fn * 16 + l15) > row) sa[fn][r] = -INFINITY;
        }
      }
#pragma unroll
      for (int fn = 0; fn < 4; ++fn)
#pragma unroll
        for (int r = 0; r < 4; ++r) sa[fn][r] = ex2(sa[fn][r]);

#pragma unroll
      for (int r = 0; r < 4; ++r) {
        const int prow = rowbase + r;
#pragma unroll
        for (int fn = 0; fn < 4; ++fn) {
          const int col = fn * 16 + l15;
          const int gp = (col >> 3) ^ (prow & 7);
          S[prow * 64 + gp * 8 + (col & 7)] = bfc(sa[fn][r]);
        }
      }

#pragma unroll
      for (int kk = 0; kk < 2; ++kk) {
        const int rp = w * 16 + l15;
        const int gp = ((kk << 2) | lg) ^ (rp & 7);
        const short8 pf = *(const short8*)&S[rp * 64 + gp * 8];
        short8 vf[4];
#pragma unroll
        for (int fd = 0; fd < 4; ++fd) {
          const int rd = fd * 16 + l15;
          const int gv = ((kk << 2) | lg) ^ (rd & 7);
          vf[fd] = *(const short8*)&S[vOff + rd * 64 + gv * 8];
        }
        __builtin_amdgcn_s_setprio(1);
#pragma unroll
        for (int fd = 0; fd < 4; ++fd)
          oa[fd] = __builtin_amdgcn_mfma_f32_16x16x32_bf16(pf, vf[fd], oa[fd], 0, 0, 0);
        oe = __builtin_amdgcn_mfma_f32_16x16x32_bf16(pf, ones, oe, 0, 0, 0);
        __builtin_amdgcn_s_setprio(0);
      }

      __syncthreads();
    }

#pragma unroll
    for (int r = 0; r < 4; ++r) {
      const float inv = 1.0f / oe[r];
      const size_t row = qrow0 + rowbase + r;
#pragma unroll
      for (int fd = 0; fd < 4; ++fd)
        attnb[row * 2048 + h * 64 + fd * 16 + l15] = f2bf(oa[fd][r] * inv);
    }

    if (sub == 0) {
      STAGE_Q(qts1);
      __syncthreads();
    }
  }
#undef STAGE_KV
#undef STAGE_Q
}

// ---------------------------------------------------------------------------
extern "C" void kernel_launch(void* const* d_in, const int* in_sizes, int n_in,
                              void* d_out, int out_size, void* d_ws, size_t ws_size,
                              hipStream_t stream) {
  (void)in_sizes; (void)n_in; (void)out_size; (void)ws_size;
  const float* x  = (const float*)d_in[0];
  const float* Wq = (const float*)d_in[1];
  const float* Wk = (const float*)d_in[2];
  const float* Wv = (const float*)d_in[3];
  const float* Wp = (const float*)d_in[4];

  // workspace layout:
  //   [0,16M)     xb (x bf16)
  //   [16M,28M)   Wt ([Wq*qs|Wk|Wv]^T)
  //   [28M,36M)   Wpt (Wp^T)
  //   [36M,52M)   qb  bf16 [4096][2048]
  //   [52M,56M)   kb  bf16 [4096][512]
  //   [76M,80M)   vt  bf16 [(b*8+kvh)*64+d][1024]
  //   [80M,96M)   attnb bf16 [4096][2048]
  //   [96M,+256K) rope table float2[1024][32]
  char* w = (char*)d_ws;
  unsigned short* xb    = (unsigned short*)(w);
  unsigned short* Wt    = (unsigned short*)(w + 16777216);
  unsigned short* Wpt   = (unsigned short*)(w + 29360128);
  unsigned short* qb    = (unsigned short*)(w + 37748736);
  unsigned short* kbuf  = (unsigned short*)(w + 54525952);
  unsigned short* vtb   = (unsigned short*)(w + 79691776);
  unsigned short* attnb = (unsigned short*)(w + 83886080);
  float2*         rtab  = (float2*)(w + 100663296);
  float* out = (float*)d_out;

  rope_tab_kernel<<<128, 256, 0, stream>>>(rtab);
  cvt_bf16_kernel<<<8192, 256, 0, stream>>>(x, xb, 2097152);
  transpose_w_kernel<<<dim3(64, 64, 4), 256, 0, stream>>>(Wq, Wk, Wv, Wp, Wt, Wpt);

  // QKV projection: 256x192 tiles, dbuf B, packed bf16 Q/K epilogue
  gemm256x192_qkv_kernel<<<dim3(16, 16), 512, 0, stream>>>(xb, Wt, qb, kbuf, vtb);
  // in-place table RoPE on bf16 qb/kb
  rope_bf16_kernel<<<5120, 256, 0, stream>>>(rtab, qb, kbuf);
  // flash attention
  attn_mfma_kernel<<<dim3(8, 32, 4), 256, 0, stream>>>(qb, kbuf, vtb, attnb);
  // output projection: 256x128 tiles -> 256 blocks, full CU fill
  gemm256x128_kernel<<<dim3(16, 16), 512, 0, stream>>>(attnb, Wpt, out, 2048, 2048);
}

// Round 21
// 161.990 us; speedup vs baseline: 1.0269x; 1.0018x over previous
//
#include <hip/hip_runtime.h>
#include <hip/hip_bf16.h>

// ---------------------------------------------------------------------------
// SelfAttention fused pipeline for MI355X (gfx950)
//   QKV GEMM 256x192 6-phase dbuf-B (256 blocks full fill); Q/K epilogue =
//   LDS round-trip -> coalesced short8 bf16 stores; V^T bf16 direct;
//   in-place table RoPE on bf16; bf16 MFMA attention (no-max log2 softmax);
//   projection GEMM 256x128 (256 blocks full fill).
// ---------------------------------------------------------------------------

typedef __attribute__((ext_vector_type(4))) float f32x4;
typedef __attribute__((ext_vector_type(8))) short short8;

#define AS1C(p) ((const __attribute__((address_space(1))) void*)(p))
#define AS3(p)  ((__attribute__((address_space(3))) void*)(p))

__device__ __forceinline__ unsigned short f2bf(float f) {
  union { float f; unsigned int u; } x; x.f = f;
  unsigned int r = x.u + 0x7FFFu + ((x.u >> 16) & 1u);
  return (unsigned short)(r >> 16);
}

__device__ __forceinline__ unsigned short bfc(float f) {
  return __bfloat16_as_ushort(__float2bfloat16(f));
}

__device__ __forceinline__ float bf2f(unsigned short u) {
  union { float f; unsigned int v; } x; x.v = ((unsigned int)u) << 16;
  return x.f;
}

__device__ __forceinline__ float ex2(float x) {
  return __builtin_amdgcn_exp2f(x);
}

// -------------------- RoPE table: tab[t*32+i] = (cos, sin) ------------------
__global__ void rope_tab_kernel(float2* __restrict__ tab) {
  const int idx = blockIdx.x * 256 + threadIdx.x;  // 32768
  const int t = idx >> 5, i = idx & 31;
  const float invf = exp2f(-(float)i * 0.41524101186092029f);
  float sv, cv;
  __sincosf((float)t * invf, &sv, &cv);
  tab[idx] = make_float2(cv, sv);
}

// -------------------- x : f32 -> bf16 (vectorized) -------------------------
__global__ void cvt_bf16_kernel(const float* __restrict__ src,
                                unsigned short* __restrict__ dst, int n4) {
  int i = blockIdx.x * blockDim.x + threadIdx.x;
  if (i >= n4) return;
  const f32x4 v = *(const f32x4*)(src + (size_t)i * 4);
  ushort4 u = make_ushort4(f2bf(v[0]), f2bf(v[1]), f2bf(v[2]), f2bf(v[3]));
  *(ushort4*)(dst + (size_t)i * 4) = u;
}

// -- fused W transpose: z=0 Wq(*qs) z=1 Wk z=2 Wv -> Wt; z=3 Wp -> Wpt -------
__global__ void transpose_w_kernel(const float* __restrict__ Wq,
                                   const float* __restrict__ Wk,
                                   const float* __restrict__ Wv,
                                   const float* __restrict__ Wp,
                                   unsigned short* __restrict__ Wt,
                                   unsigned short* __restrict__ Wpt) {
  __shared__ float tile[32][33];
  const int z = blockIdx.z;
  const float* src;
  unsigned short* dst;
  int N, rowOff;
  float scale = 1.0f;
  if (z == 0)      { src = Wq; dst = Wt;  N = 2048; rowOff = 0;    scale = 0.18033688011112042f; }
  else if (z == 1) { src = Wk; dst = Wt;  N = 512;  rowOff = 2048; }
  else if (z == 2) { src = Wv; dst = Wt;  N = 512;  rowOff = 2560; }
  else             { src = Wp; dst = Wpt; N = 2048; rowOff = 0;    }
  const int n0 = blockIdx.x * 32, k0 = blockIdx.y * 32;
  if (n0 >= N) return;
  const int tx = threadIdx.x & 31, ty = threadIdx.x >> 5;
#pragma unroll
  for (int i = ty; i < 32; i += 8)
    tile[i][tx] = src[(size_t)(k0 + i) * N + (n0 + tx)];
  __syncthreads();
#pragma unroll
  for (int i = ty; i < 32; i += 8)
    dst[(size_t)(rowOff + n0 + i) * 2048 + (k0 + tx)] = f2bf(tile[tx][i] * scale);
}

// ---- wide RoPE (in-place, bf16): 8 elems/thread, table-based ---------------
__global__ void rope_bf16_kernel(const float2* __restrict__ tab,
                                 unsigned short* __restrict__ qb,
                                 unsigned short* __restrict__ kb) {
  const int idx = blockIdx.x * 256 + threadIdx.x;  // 4096*320
  const int m = idx / 320;
  const int p = idx - m * 320;
  const int t = m & 1023;
  unsigned short* base;
  int col;
  if (p < 256) { base = qb + (size_t)m * 2048; col = p * 8; }
  else         { base = kb + (size_t)m * 512;  col = (p - 256) * 8; }
  const int i0 = (col & 63) >> 1;
  short8 v = *(short8*)(base + col);
  short8 o;
#pragma unroll
  for (int j = 0; j < 4; ++j) {
    const float2 cs = tab[t * 32 + i0 + j];
    const float x1 = bf2f((unsigned short)v[2 * j]);
    const float x2 = bf2f((unsigned short)v[2 * j + 1]);
    o[2 * j]     = (short)bfc(x1 * cs.x - x2 * cs.y);
    o[2 * j + 1] = (short)bfc(x2 * cs.x + x1 * cs.y);
  }
  *(short8*)(base + col) = o;
}

#define BAR() __builtin_amdgcn_s_barrier()

// =========== 256x192 QKV GEMM: 256 blocks, 8 waves = 4M x 2N ================
// LDS 112 KiB (shorts): A buf(tile&1) @ tile<<14 (256x64 each); B buf(tile&1)
// @ 32768 + (tile&1)*12288 (192x64 each). Granule-XOR swizzle both-sides;
// XCD-chunked block swizzle. 6 phases / 2 K-tiles (R18 schedule, dbuf B,
// gates vmcnt(5) @P3/P6). Q/K epilogue: LDS round-trip -> coalesced short8.
#define SA3(tile, half)                                                                  \
  do {                                                                                   \
    const unsigned short* p_ = Ap + (size_t)(m0 + (half) * 128 + sr) * 2048 + (tile) * 64 + sc; \
    const int d_ = (((tile) & 1) << 14) + ((half) << 13) + tid * 8;                      \
    __builtin_amdgcn_global_load_lds(AS1C(p_), AS3(&S[d_]), 16, 0, 0);                   \
    __builtin_amdgcn_global_load_lds(AS1C(p_ + (size_t)64 * 2048), AS3(&S[d_ + 4096]), 16, 0, 0); \
  } while (0)

#define SB3(tile, u)                                                                     \
  do {                                                                                   \
    const unsigned short* p_ = Bp + (size_t)(n0 + (u) * 64 + sr) * 2048 + (tile) * 64 + sc; \
    const int d_ = 32768 + ((tile) & 1) * 12288 + (u) * 4096 + tid * 8;                  \
    __builtin_amdgcn_global_load_lds(AS1C(p_), AS3(&S[d_]), 16, 0, 0);                   \
  } while (0)

#define RDA3(tile)                                                                       \
  _Pragma("unroll") for (int kk = 0; kk < 2; ++kk)                                       \
  _Pragma("unroll") for (int fm = 0; fm < 4; ++fm) {                                     \
    const int r_ = mg * 64 + fm * 16 + l15;                                              \
    af[kk][fm] = *(const short8*)&S[(((tile) & 1) << 14) + r_ * 64 +                     \
                                    (((kk << 2) | lg) ^ (r_ & 7)) * 8];                  \
  }

#define RDB3(tile, p)                                                                    \
  _Pragma("unroll") for (int kk = 0; kk < 2; ++kk)                                       \
  _Pragma("unroll") for (int jj = 0; jj < 2; ++jj) {                                     \
    const int r_ = ng * 96 + ((p) * 2 + jj) * 16 + l15;                                  \
    bf[kk][jj] = *(const short8*)&S[32768 + ((tile) & 1) * 12288 + r_ * 64 +             \
                                    (((kk << 2) | lg) ^ (r_ & 7)) * 8];                  \
  }

#define MM3(p)                                                                           \
  do {                                                                                   \
    __builtin_amdgcn_s_setprio(1);                                                       \
    _Pragma("unroll") for (int kk = 0; kk < 2; ++kk)                                     \
    _Pragma("unroll") for (int fm = 0; fm < 4; ++fm)                                     \
    _Pragma("unroll") for (int jj = 0; jj < 2; ++jj)                                     \
      acc[fm][(p) * 2 + jj] = __builtin_amdgcn_mfma_f32_16x16x32_bf16(                   \
          af[kk][fm], bf[kk][jj], acc[fm][(p) * 2 + jj], 0, 0, 0);                       \
    __builtin_amdgcn_s_setprio(0);                                                       \
  } while (0)

__global__ __launch_bounds__(512, 1) void gemm256x192_qkv_kernel(
    const unsigned short* __restrict__ Ap, const unsigned short* __restrict__ Bp,
    unsigned short* __restrict__ qb, unsigned short* __restrict__ kb,
    unsigned short* __restrict__ vt) {
  __shared__ unsigned short S[57344];  // 112 KiB
  const int tid = threadIdx.x;
  const int lane = tid & 63, w = tid >> 6;
  const int l15 = lane & 15, lg = lane >> 4;
  int lid = blockIdx.x + 16 * blockIdx.y;          // 256 blocks
  lid = (lid & 7) * 32 + (lid >> 3);               // bijective XCD chunk
  const int m0 = (lid >> 4) * 256, n0 = (lid & 15) * 192;
  const int mg = w >> 1;   // 4 M-groups of 64 rows
  const int ng = w & 1;    // 2 N-groups of 96 cols
  const int sr = tid >> 3;
  const int sc = ((tid & 7) ^ (sr & 7)) << 3;
  const int NT = 32;       // K=2048

  f32x4 acc[4][6];
#pragma unroll
  for (int i = 0; i < 4; ++i)
#pragma unroll
    for (int j = 0; j < 6; ++j)
#pragma unroll
      for (int c = 0; c < 4; ++c) acc[i][j][c] = 0.f;

  // prologue: A(0), B(0) full; A(1), B(1)u0 (B(1)u1,u2 deferred to P1)
  SA3(0, 0); SA3(0, 1); SB3(0, 0); SB3(0, 1); SB3(0, 2);
  SA3(1, 0); SA3(1, 1); SB3(1, 0);
  asm volatile("s_waitcnt vmcnt(5)" ::: "memory");  // tile-0 data retired
  BAR();

  short8 af[2][4], bf[2][2];

  for (int t = 0; t < NT; t += 2) {
    const bool nl = (t + 2 < NT);
    // P1: read A(t), B(t)p0; stage B(t+1)u1,u2 (regions freed prev-P6)
    RDA3(t); RDB3(t, 0);
    SB3(t + 1, 1); SB3(t + 1, 2);
    BAR();
    MM3(0);
    BAR();
    // P2: read B(t)p1; stage A(t+2)h0 (A(t) fully read in P1)
    RDB3(t, 1);
    if (nl) SA3(t + 2, 0);
    BAR();
    MM3(1);
    BAR();
    // P3: read B(t)p2; stage A(t+2)h1, B(t+2)u0; gate: P1's loads retired
    RDB3(t, 2);
    if (nl) {
      SA3(t + 2, 1); SB3(t + 2, 0);
      asm volatile("s_waitcnt vmcnt(5)" ::: "memory");
    } else {
      asm volatile("s_waitcnt vmcnt(0)" ::: "memory");
    }
    BAR();
    MM3(2);
    BAR();
    // P4: read A(t+1), B(t+1)p0; stage B(t+2)u1,u2 (freed after P3)
    RDA3(t + 1); RDB3(t + 1, 0);
    if (nl) { SB3(t + 2, 1); SB3(t + 2, 2); }
    BAR();
    MM3(0);
    BAR();
    // P5: read B(t+1)p1; stage A(t+3)h0 (A(t+1) fully read in P4)
    RDB3(t + 1, 1);
    if (nl) SA3(t + 3, 0);
    BAR();
    MM3(1);
    BAR();
    // P6: read B(t+1)p2; stage A(t+3)h1, B(t+3)u0; gate: t+2 loads retired
    RDB3(t + 1, 2);
    if (nl) {
      SA3(t + 3, 1); SB3(t + 3, 0);
      asm volatile("s_waitcnt vmcnt(5)" ::: "memory");
    }
    BAR();
    MM3(2);
    BAR();
  }

  // ---- epilogue ----
  // Q/K fragments -> LDS [256][192] bf16; V fragments -> direct packed store.
  const int colQK = n0 >= 2560 ? 0 : (n0 >= 2432 ? 2560 - n0 : 192);
#pragma unroll
  for (int fn = 0; fn < 6; ++fn) {
    const int col16 = n0 + ng * 96 + fn * 16;
    if (col16 < 2560) {
      const int colL = ng * 96 + fn * 16 + l15;
#pragma unroll
      for (int fm = 0; fm < 4; ++fm) {
        const int row = mg * 64 + fm * 16 + lg * 4;
#pragma unroll
        for (int r = 0; r < 4; ++r)
          S[(row + r) * 192 + colL] = bfc(acc[fm][fn][r]);
      }
    } else {
      // V: packed transposed bf16 store
      const int dz = (col16 - 2560) >> 6;
      const int d = ((col16 - 2560) & 63) + l15;
#pragma unroll
      for (int fm = 0; fm < 4; ++fm) {
        const int row = m0 + mg * 64 + fm * 16 + lg * 4;
        const int z = (row >> 10) * 8 + dz;
        const int t0 = row & 1023;
        ushort4 u = make_ushort4(bfc(acc[fm][fn][0]), bfc(acc[fm][fn][1]),
                                 bfc(acc[fm][fn][2]), bfc(acc[fm][fn][3]));
        *(ushort4*)&vt[(size_t)z * 65536 + d * 1024 + t0] = u;
      }
    }
  }
  if (colQK > 0) {
    BAR();  // LDS tile complete (block-uniform branch)
    const int cpr = colQK >> 3;          // short8 chunks per row: 8 or 24
    const int total = 256 * cpr;
    for (int c = tid; c < total; c += 512) {
      const int row = c / cpr;
      const int cc = (c - row * cpr) * 8;
      const short8 v = *(const short8*)&S[row * 192 + cc];
      const int gcol = n0 + cc;
      if (gcol < 2048)
        *(short8*)&qb[(size_t)(m0 + row) * 2048 + gcol] = v;
      else
        *(short8*)&kb[(size_t)(m0 + row) * 512 + (gcol - 2048)] = v;
    }
  }
}

// ============ 256x128 GEMM (projection): 8 waves 2Mx4N (32-col strips) ======
#define SA2(tile, half)                                                                  \
  do {                                                                                   \
    const unsigned short* p_ = Ap + (size_t)(m0 + (half) * 128 + sr) * Kd + (tile) * 64 + sc; \
    const int d_ = (((tile) & 1) << 14) + ((half) << 13) + tid * 8;                      \
    __builtin_amdgcn_global_load_lds(AS1C(p_), AS3(&S[d_]), 16, 0, 0);                   \
    __builtin_amdgcn_global_load_lds(AS1C(p_ + (size_t)64 * Kd), AS3(&S[d_ + 4096]), 16, 0, 0); \
  } while (0)

#define SB2(tile)                                                                        \
  do {                                                                                   \
    const unsigned short* p_ = Bp + (size_t)(n0 + sr) * Kd + (tile) * 64 + sc;           \
    const int d_ = 32768 + (((tile) & 1) << 13) + tid * 8;                               \
    __builtin_amdgcn_global_load_lds(AS1C(p_), AS3(&S[d_]), 16, 0, 0);                   \
    __builtin_amdgcn_global_load_lds(AS1C(p_ + (size_t)64 * Kd), AS3(&S[d_ + 4096]), 16, 0, 0); \
  } while (0)

#define RDA2(tile, Msub)                                                                 \
  _Pragma("unroll") for (int kk = 0; kk < 2; ++kk)                                       \
  _Pragma("unroll") for (int fm = 0; fm < 4; ++fm) {                                     \
    const int r_ = (Msub) * 64 + fm * 16 + l15;                                          \
    af[kk][fm] = *(const short8*)&S[(((tile) & 1) << 14) + (ah << 13) + r_ * 64 +        \
                                    (((kk << 2) | lg) ^ (r_ & 7)) * 8];                  \
  }

#define RDB2(dst, tile)                                                                  \
  _Pragma("unroll") for (int kk = 0; kk < 2; ++kk)                                       \
  _Pragma("unroll") for (int j = 0; j < 2; ++j) {                                        \
    const int r_ = wn + j * 16 + l15;                                                    \
    dst[kk][j] = *(const short8*)&S[32768 + (((tile) & 1) << 13) + r_ * 64 +             \
                                    (((kk << 2) | lg) ^ (r_ & 7)) * 8];                  \
  }

#define MM2(Msub, bb)                                                                    \
  do {                                                                                   \
    __builtin_amdgcn_s_setprio(1);                                                       \
    _Pragma("unroll") for (int kk = 0; kk < 2; ++kk)                                     \
    _Pragma("unroll") for (int fm = 0; fm < 4; ++fm)                                     \
    _Pragma("unroll") for (int j = 0; j < 2; ++j)                                        \
      acc[(Msub) * 4 + fm][j] = __builtin_amdgcn_mfma_f32_16x16x32_bf16(                 \
          af[kk][fm], bb[kk][j], acc[(Msub) * 4 + fm][j], 0, 0, 0);                      \
    __builtin_amdgcn_s_setprio(0);                                                       \
  } while (0)

__global__ __launch_bounds__(512, 1) void gemm256x128_kernel(
    const unsigned short* __restrict__ Ap, const unsigned short* __restrict__ Bp,
    float* __restrict__ C, int K, int N) {
  __shared__ unsigned short S[49152];  // 96 KiB
  const int tid = threadIdx.x;
  const int lane = tid & 63, w = tid >> 6;
  const int l15 = lane & 15, lg = lane >> 4;
  const int nwgx = gridDim.x;  // N/128
  const int nwg = nwgx * gridDim.y;
  int lid = blockIdx.x + nwgx * blockIdx.y;
  lid = (lid & 7) * (nwg >> 3) + (lid >> 3);
  const int m0 = (lid / nwgx) * 256, n0 = (lid % nwgx) * 128;
  const int ah = w >> 2;
  const int wn = (w & 3) * 32;
  const int NT = K >> 6;
  const int Kd = K;
  const int sr = tid >> 3;
  const int sc = ((tid & 7) ^ (sr & 7)) << 3;

  f32x4 acc[8][2];
#pragma unroll
  for (int i = 0; i < 8; ++i)
#pragma unroll
    for (int j = 0; j < 2; ++j)
#pragma unroll
      for (int c = 0; c < 4; ++c) acc[i][j][c] = 0.f;

  SB2(0); SA2(0, 0); SA2(0, 1); SB2(1); SA2(1, 0);
  asm volatile("s_waitcnt vmcnt(4)" ::: "memory");
  __builtin_amdgcn_s_barrier();

  short8 af[2][4], b0[2][2], b1[2][2];

  for (int t = 0; t < NT; t += 2) {
    const bool nl = (t + 2 < NT);
    RDA2(t, 0); RDB2(b0, t);
    SA2(t + 1, 1);
    BAR();
    MM2(0, b0);
    BAR();
    RDA2(t, 1);
    if (nl) {
      SB2(t + 2); SA2(t + 2, 0);
      asm volatile("s_waitcnt vmcnt(4)" ::: "memory");
    } else {
      asm volatile("s_waitcnt vmcnt(0)" ::: "memory");
    }
    BAR();
    MM2(1, b0);
    BAR();
    RDA2(t + 1, 0); RDB2(b1, t + 1);
    if (nl) SA2(t + 2, 1);
    BAR();
    MM2(0, b1);
    BAR();
    RDA2(t + 1, 1);
    if (nl) {
      SB2(t + 3); SA2(t + 3, 0);
      asm volatile("s_waitcnt vmcnt(4)" ::: "memory");
    }
    BAR();
    MM2(1, b1);
    BAR();
  }

#pragma unroll
  for (int fm8 = 0; fm8 < 8; ++fm8)
#pragma unroll
    for (int j = 0; j < 2; ++j) {
      const size_t base =
          (size_t)(m0 + ah * 128 + (fm8 >> 2) * 64 + (fm8 & 3) * 16 + lg * 4) * N +
          (n0 + wn + j * 16 + l15);
#pragma unroll
      for (int r = 0; r < 4; ++r) C[base + (size_t)r * N] = acc[fm8][j][r];
    }
}

// -------------------- bf16 MFMA flash attention (causal, GQA 4:1) -----------
__global__ __launch_bounds__(256) void attn_mfma_kernel(
    const unsigned short* __restrict__ qb, const unsigned short* __restrict__ kb,
    const unsigned short* __restrict__ vt, unsigned short* __restrict__ attnb) {
  int lid = blockIdx.x + 8 * (blockIdx.y + 32 * blockIdx.z);  // 1024 blocks
  lid = (lid & 7) * 128 + (lid >> 3);                         // bijective chunk
  const int bx = lid & 7, h = (lid >> 3) & 31, b = lid >> 8;
  const int kvh = h >> 2;
  __shared__ unsigned short S[20480];  // 40 KiB
  const int tid = threadIdx.x, lane = tid & 63, w = tid >> 6;
  const int l15 = lane & 15, lg = lane >> 4;
  const int rowbase = w * 16 + lg * 4;

  const int gi0 = w * 64 + lane;
  const int r0 = gi0 >> 3, g0 = (gi0 & 7) ^ (r0 & 7);
  const int gi1 = (4 + w) * 64 + lane;
  const int r1 = gi1 >> 3, g1 = (gi1 & 7) ^ (r1 & 7);

  const unsigned short* kbase = kb + (size_t)b * 1024 * 512 + kvh * 64;
  const unsigned short* vbase = vt + (size_t)(b * 8 + kvh) * 64 * 1024;

#define STAGE_KV(kOff, vOff, jj)                                                    \
  do {                                                                              \
    __builtin_amdgcn_global_load_lds(AS1C(kbase + ((jj) * 64 + r0) * 512 + g0 * 8), \
                                     AS3(&S[(kOff) + w * 512]), 16, 0, 0);          \
    __builtin_amdgcn_global_load_lds(AS1C(kbase + ((jj) * 64 + r1) * 512 + g1 * 8), \
                                     AS3(&S[(kOff) + (4 + w) * 512]), 16, 0, 0);    \
    __builtin_amdgcn_global_load_lds(AS1C(vbase + r0 * 1024 + (jj) * 64 + g0 * 8),  \
                                     AS3(&S[(vOff) + w * 512]), 16, 0, 0);          \
    __builtin_amdgcn_global_load_lds(AS1C(vbase + r1 * 1024 + (jj) * 64 + g1 * 8),  \
                                     AS3(&S[(vOff) + (4 + w) * 512]), 16, 0, 0);    \
  } while (0)

#define STAGE_Q(qt)                                                                     \
  do {                                                                                  \
    const size_t qr_ = (size_t)b * 1024 + (qt) * 64;                                    \
    __builtin_amdgcn_global_load_lds(AS1C(qb + (qr_ + r0) * 2048 + h * 64 + g0 * 8),    \
                                     AS3(&S[w * 512]), 16, 0, 0);                       \
    __builtin_amdgcn_global_load_lds(AS1C(qb + (qr_ + r1) * 2048 + h * 64 + g1 * 8),    \
                                     AS3(&S[(4 + w) * 512]), 16, 0, 0);                 \
  } while (0)

  const int qts0 = bx, qts1 = 15 - bx;

  short8 ones;
#pragma unroll
  for (int i = 0; i < 8; ++i) ones[i] = (short)0x3F80;  // bf16 1.0

  STAGE_Q(qts0);
  STAGE_KV(4096, 12288, 0);
  __syncthreads();

  int g = 0;
  for (int sub = 0; sub < 2; ++sub) {
    const int qtc = sub ? qts1 : qts0;
    const size_t qrow0 = (size_t)b * 1024 + qtc * 64;

    short8 qf[2];
#pragma unroll
    for (int kk = 0; kk < 2; ++kk) {
      const int r = w * 16 + l15;
      const int gq = ((kk << 2) | lg) ^ (r & 7);
      qf[kk] = *(const short8*)&S[r * 64 + gq * 8];
    }

    f32x4 oa[4], oe;
#pragma unroll
    for (int r = 0; r < 4; ++r) oe[r] = 0.f;
#pragma unroll
    for (int fd = 0; fd < 4; ++fd)
#pragma unroll
      for (int r = 0; r < 4; ++r) oa[fd][r] = 0.f;

    for (int j = 0; j <= qtc; ++j, ++g) {
      const int cur = g & 1;
      const int kOff = 4096 + cur * 4096;
      const int vOff = 12288 + cur * 4096;
      if (g < 16) {
        const int nj = (g + 1 <= qts0) ? g + 1 : g - qts0;
        STAGE_KV(4096 + (cur ^ 1) * 4096, 12288 + (cur ^ 1) * 4096, nj);
      }

      f32x4 sa[4];
#pragma unroll
      for (int fn = 0; fn < 4; ++fn)
#pragma unroll
        for (int r = 0; r < 4; ++r) sa[fn][r] = 0.f;
#pragma unroll
      for (int kk = 0; kk < 2; ++kk) {
        short8 kf[4];
#pragma unroll
        for (int fn = 0; fn < 4; ++fn) {
          const int rkv = fn * 16 + l15;
          const int gk = ((kk << 2) | lg) ^ (rkv & 7);
          kf[fn] = *(const short8*)&S[kOff + rkv * 64 + gk * 8];
        }
        __builtin_amdgcn_s_setprio(1);
#pragma unroll
        for (int fn = 0; fn < 4; ++fn)
          sa[fn] = __builtin_amdgcn_mfma_f32_16x16x32_bf16(qf[kk], kf[fn], sa[fn], 0, 0, 0);
        __builtin_amdgcn_s_setprio(0);
      }

      if (j == qtc) {
#pragma unroll
        for (int r = 0; r < 4; ++r) {
          const int row = rowbase + r;
#pragma unroll
          for (int fn = 0; fn < 4; ++fn)
            if ((fn * 16 + l15) > row) sa[fn][r] = -INFINITY;
        }
      }
#pragma unroll
      for (int fn = 0; fn < 4; ++fn)
#pragma unroll
        for (int r = 0; r < 4; ++r) sa[fn][r] = ex2(sa[fn][r]);

#pragma unroll
      for (int r = 0; r < 4; ++r) {
        const int prow = rowbase + r;
#pragma unroll
        for (int fn = 0; fn < 4; ++fn) {
          const int col = fn * 16 + l15;
          const int gp = (col >> 3) ^ (prow & 7);
          S[prow * 64 + gp * 8 + (col & 7)] = bfc(sa[fn][r]);
        }
      }

#pragma unroll
      for (int kk = 0; kk < 2; ++kk) {
        const int rp = w * 16 + l15;
        const int gp = ((kk << 2) | lg) ^ (rp & 7);
        const short8 pf = *(const short8*)&S[rp * 64 + gp * 8];
        short8 vf[4];
#pragma unroll
        for (int fd = 0; fd < 4; ++fd) {
          const int rd = fd * 16 + l15;
          const int gv = ((kk << 2) | lg) ^ (rd & 7);
          vf[fd] = *(const short8*)&S[vOff + rd * 64 + gv * 8];
        }
        __builtin_amdgcn_s_setprio(1);
#pragma unroll
        for (int fd = 0; fd < 4; ++fd)
          oa[fd] = __builtin_amdgcn_mfma_f32_16x16x32_bf16(pf, vf[fd], oa[fd], 0, 0, 0);
        oe = __builtin_amdgcn_mfma_f32_16x16x32_bf16(pf, ones, oe, 0, 0, 0);
        __builtin_amdgcn_s_setprio(0);
      }

      __syncthreads();
    }

#pragma unroll
    for (int r = 0; r < 4; ++r) {
      const float inv = 1.0f / oe[r];
      const size_t row = qrow0 + rowbase + r;
#pragma unroll
      for (int fd = 0; fd < 4; ++fd)
        attnb[row * 2048 + h * 64 + fd * 16 + l15] = f2bf(oa[fd][r] * inv);
    }

    if (sub == 0) {
      STAGE_Q(qts1);
      __syncthreads();
    }
  }
#undef STAGE_KV
#undef STAGE_Q
}

// ---------------------------------------------------------------------------
extern "C" void kernel_launch(void* const* d_in, const int* in_sizes, int n_in,
                              void* d_out, int out_size, void* d_ws, size_t ws_size,
                              hipStream_t stream) {
  (void)in_sizes; (void)n_in; (void)out_size; (void)ws_size;
  const float* x  = (const float*)d_in[0];
  const float* Wq = (const float*)d_in[1];
  const float* Wk = (const float*)d_in[2];
  const float* Wv = (const float*)d_in[3];
  const float* Wp = (const float*)d_in[4];

  // workspace layout:
  //   [0,16M)     xb (x bf16)
  //   [16M,28M)   Wt ([Wq*qs|Wk|Wv]^T)
  //   [28M,36M)   Wpt (Wp^T)
  //   [36M,52M)   qb  bf16 [4096][2048]
  //   [52M,56M)   kb  bf16 [4096][512]
  //   [76M,80M)   vt  bf16 [(b*8+kvh)*64+d][1024]
  //   [80M,96M)   attnb bf16 [4096][2048]
  //   [96M,+256K) rope table float2[1024][32]
  char* w = (char*)d_ws;
  unsigned short* xb    = (unsigned short*)(w);
  unsigned short* Wt    = (unsigned short*)(w + 16777216);
  unsigned short* Wpt   = (unsigned short*)(w + 29360128);
  unsigned short* qb    = (unsigned short*)(w + 37748736);
  unsigned short* kbuf  = (unsigned short*)(w + 54525952);
  unsigned short* vtb   = (unsigned short*)(w + 79691776);
  unsigned short* attnb = (unsigned short*)(w + 83886080);
  float2*         rtab  = (float2*)(w + 100663296);
  float* out = (float*)d_out;

  rope_tab_kernel<<<128, 256, 0, stream>>>(rtab);
  cvt_bf16_kernel<<<8192, 256, 0, stream>>>(x, xb, 2097152);
  transpose_w_kernel<<<dim3(64, 64, 4), 256, 0, stream>>>(Wq, Wk, Wv, Wp, Wt, Wpt);

  // QKV projection: 256x192 tiles, dbuf B, LDS round-trip bf16 epilogue
  gemm256x192_qkv_kernel<<<dim3(16, 16), 512, 0, stream>>>(xb, Wt, qb, kbuf, vtb);
  // in-place table RoPE on bf16 qb/kb
  rope_bf16_kernel<<<5120, 256, 0, stream>>>(rtab, qb, kbuf);
  // flash attention
  attn_mfma_kernel<<<dim3(8, 32, 4), 256, 0, stream>>>(qb, kbuf, vtb, attnb);
  // output projection: 256x128 tiles -> 256 blocks, full CU fill
  gemm256x128_kernel<<<dim3(16, 16), 512, 0, stream>>>(attnb, Wpt, out, 2048, 2048);
}